// Round 1
// baseline (553.346 us; speedup 1.0000x reference)
//
#include <hip/hip_runtime.h>
#include <float.h>

// ---------------------------------------------------------------------------
// L1-distance top-K (K<=3) over N=200000 rows of D=512 fp32, then mean of
// pseudo[] at the top-K indices. Memory-bound: one streaming pass over
// ukb_mat (409.6 MB). One wave (64 lanes) per row, coalesced float4 loads,
// shuffle-butterfly row reduction, per-wave running top-3, two-phase select.
// ---------------------------------------------------------------------------

#define P1_BLOCKS       1024
#define P1_THREADS      256
#define WAVES_PER_BLOCK (P1_THREADS / 64)
#define TOTAL_WAVES     (P1_BLOCKS * WAVES_PER_BLOCK)
#define NUM_PART        (TOTAL_WAVES * 3)
#define DCOLS           512

// Insert candidate (s, r) into sorted top-3 (d0<=d1<=d2). Ties prefer the
// smaller index (matches jax.lax.top_k stability on -dist).
__device__ __forceinline__ void top3_insert(float s, int r,
                                            float& d0, float& d1, float& d2,
                                            int& i0, int& i1, int& i2) {
    if (s < d2 || (s == d2 && r < i2)) {
        d2 = s; i2 = r;
        if (d2 < d1 || (d2 == d1 && i2 < i1)) {
            float td = d1; d1 = d2; d2 = td;
            int   ti = i1; i1 = i2; i2 = ti;
        }
        if (d1 < d0 || (d1 == d0 && i1 < i0)) {
            float td = d0; d0 = d1; d1 = td;
            int   ti = i0; i0 = i1; i1 = ti;
        }
    }
}

__global__ __launch_bounds__(P1_THREADS) void l1_top3_phase1(
        const float* __restrict__ q, const float* __restrict__ mat,
        float* __restrict__ part_d, int* __restrict__ part_i, int N) {
    const int lane = threadIdx.x & 63;
    const int wave = blockIdx.x * WAVES_PER_BLOCK + (threadIdx.x >> 6);

    // Query fragment in registers: lane i holds q[4i..4i+4) and q[256+4i..).
    const float4 q0 = ((const float4*)q)[lane];
    const float4 q1 = ((const float4*)q)[64 + lane];

    float d0 = FLT_MAX, d1 = FLT_MAX, d2 = FLT_MAX;
    int   i0 = -1, i1 = -1, i2 = -1;

    for (int row = wave; row < N; row += TOTAL_WAVES) {
        const float4* rp = (const float4*)(mat + (size_t)row * DCOLS);
        float4 a = rp[lane];        // bytes [16*lane, +16)        — coalesced
        float4 b = rp[64 + lane];   // bytes [1024+16*lane, +16)   — coalesced
        float s = fabsf(a.x - q0.x) + fabsf(a.y - q0.y)
                + fabsf(a.z - q0.z) + fabsf(a.w - q0.w)
                + fabsf(b.x - q1.x) + fabsf(b.y - q1.y)
                + fabsf(b.z - q1.z) + fabsf(b.w - q1.w);
        // 64-lane butterfly sum (wave = 64 on CDNA!)
        #pragma unroll
        for (int m = 32; m >= 1; m >>= 1) s += __shfl_xor(s, m, 64);
        // rows strictly increase per wave, so strict < keeps the earliest
        // index on exact ties — matches reference tie order.
        top3_insert(s, row, d0, d1, d2, i0, i1, i2);
    }
    if (lane == 0) {
        part_d[wave * 3 + 0] = d0; part_i[wave * 3 + 0] = i0;
        part_d[wave * 3 + 1] = d1; part_i[wave * 3 + 1] = i1;
        part_d[wave * 3 + 2] = d2; part_i[wave * 3 + 2] = i2;
    }
}

__global__ __launch_bounds__(256) void top3_phase2(
        const float* __restrict__ part_d, const int* __restrict__ part_i,
        const float* __restrict__ pseudo, const int* __restrict__ Kp,
        float* __restrict__ out, int num) {
    float d0 = FLT_MAX, d1 = FLT_MAX, d2 = FLT_MAX;
    int   i0 = -1, i1 = -1, i2 = -1;

    for (int j = threadIdx.x; j < num; j += 256)
        top3_insert(part_d[j], part_i[j], d0, d1, d2, i0, i1, i2);

    __shared__ float sd[256 * 3];
    __shared__ int   si[256 * 3];
    sd[threadIdx.x * 3 + 0] = d0; si[threadIdx.x * 3 + 0] = i0;
    sd[threadIdx.x * 3 + 1] = d1; si[threadIdx.x * 3 + 1] = i1;
    sd[threadIdx.x * 3 + 2] = d2; si[threadIdx.x * 3 + 2] = i2;
    __syncthreads();

    if (threadIdx.x < 64) {  // wave 0 only — shuffles see 64 active lanes
        #pragma unroll
        for (int b = 1; b < 4; ++b) {
            int base = (threadIdx.x + b * 64) * 3;
            top3_insert(sd[base + 0], si[base + 0], d0, d1, d2, i0, i1, i2);
            top3_insert(sd[base + 1], si[base + 1], d0, d1, d2, i0, i1, i2);
            top3_insert(sd[base + 2], si[base + 2], d0, d1, d2, i0, i1, i2);
        }
        #pragma unroll
        for (int m = 32; m >= 1; m >>= 1) {
            // read partner's pre-merge triple before mutating our own
            float pd0 = __shfl_xor(d0, m, 64);
            float pd1 = __shfl_xor(d1, m, 64);
            float pd2 = __shfl_xor(d2, m, 64);
            int   pi0 = __shfl_xor(i0, m, 64);
            int   pi1 = __shfl_xor(i1, m, 64);
            int   pi2 = __shfl_xor(i2, m, 64);
            top3_insert(pd0, pi0, d0, d1, d2, i0, i1, i2);
            top3_insert(pd1, pi1, d0, d1, d2, i0, i1, i2);
            top3_insert(pd2, pi2, d0, d1, d2, i0, i1, i2);
        }
        if (threadIdx.x == 0) {
            int K = Kp[0];
            if (K < 1) K = 1;
            if (K > 3) K = 3;
            float sum = pseudo[i0];
            if (K > 1) sum += pseudo[i1];
            if (K > 2) sum += pseudo[i2];
            out[0] = sum / (float)K;
        }
    }
}

extern "C" void kernel_launch(void* const* d_in, const int* in_sizes, int n_in,
                              void* d_out, int out_size, void* d_ws, size_t ws_size,
                              hipStream_t stream) {
    const float* data_in = (const float*)d_in[0];   // [1, 512] fp32
    const float* ukb_mat = (const float*)d_in[1];   // [N, 512] fp32
    const float* pseudo  = (const float*)d_in[2];   // [N] fp32
    const int*   Kp      = (const int*)d_in[3];     // scalar int (=3)
    float*       out     = (float*)d_out;           // [1] fp32

    const int N = in_sizes[1] / DCOLS;              // 200000

    // Workspace: NUM_PART floats + NUM_PART ints (96 KB), fully overwritten
    // by phase 1 every launch before phase 2 reads it.
    float* part_d = (float*)d_ws;
    int*   part_i = (int*)((char*)d_ws + (size_t)NUM_PART * sizeof(float));

    l1_top3_phase1<<<P1_BLOCKS, P1_THREADS, 0, stream>>>(
        data_in, ukb_mat, part_d, part_i, N);
    top3_phase2<<<1, 256, 0, stream>>>(
        part_d, part_i, pseudo, Kp, out, NUM_PART);
}